// Round 1
// baseline (1598.640 us; speedup 1.0000x reference)
//
#include <hip/hip_runtime.h>
#include <stdint.h>

#define B_ 64
#define T_ 512
#define I_ 128
#define H_ 512
#define O_ 64
#define ALPHA_ 0.1f

typedef _Float16 f16;
typedef _Float16 f16x2 __attribute__((ext_vector_type(2)));

__device__ __forceinline__ uint32_t pkf16(float a, float b) {
  f16 ha = (f16)a, hb = (f16)b;
  uint16_t ua = __builtin_bit_cast(uint16_t, ha);
  uint16_t ub = __builtin_bit_cast(uint16_t, hb);
  return (uint32_t)ua | ((uint32_t)ub << 16);
}

__device__ __forceinline__ float dot2(uint32_t w, uint32_t h, float acc) {
#if __has_builtin(__builtin_amdgcn_fdot2)
  return __builtin_amdgcn_fdot2(__builtin_bit_cast(f16x2, w),
                                __builtin_bit_cast(f16x2, h), acc, false);
#else
  f16x2 wv = __builtin_bit_cast(f16x2, w), hv = __builtin_bit_cast(f16x2, h);
  return acc + (float)wv[0] * (float)hv[0] + (float)wv[1] * (float)hv[1];
#endif
}

__device__ __forceinline__ float tanhfast(float x) {
  float e = __expf(2.0f * x);   // e = exp(2x); inf-safe at both ends
#if __has_builtin(__builtin_amdgcn_rcpf)
  return 1.0f - 2.0f * __builtin_amdgcn_rcpf(e + 1.0f);
#else
  return 1.0f - 2.0f / (e + 1.0f);
#endif
}

// ---------------------------------------------------------------------------
// Pack weights into f16x2 pairs, transposed so per-thread loads are coalesced:
//   wrecT[k*512 + t] = (W_rec[t,2k], W_rec[t,2k+1])   k in [0,256)
//   winT [k*512 + n] = (W_in [n,2k], W_in [n,2k+1])   k in [0,64)
//   woutT[k*64  + o] = (W_out[o,2k], W_out[o,2k+1])   k in [0,256)
// ---------------------------------------------------------------------------
__global__ __launch_bounds__(256) void pack_w(
    const float* __restrict__ Wrec, const float* __restrict__ Win,
    const float* __restrict__ Wout, uint32_t* __restrict__ wrecT,
    uint32_t* __restrict__ winT, uint32_t* __restrict__ woutT) {
  int id = blockIdx.x * 256 + threadIdx.x;
  if (id < 512 * 256) {
    int t = id >> 8, k = id & 255;
    const float* s = Wrec + t * 512 + 2 * k;
    wrecT[k * 512 + t] = pkf16(s[0], s[1]);
  } else if (id < 512 * 256 + 512 * 64) {
    int j = id - 512 * 256;
    int n = j >> 6, k = j & 63;
    const float* s = Win + n * 128 + 2 * k;
    winT[k * 512 + n] = pkf16(s[0], s[1]);
  } else {
    int j = id - (512 * 256 + 512 * 64);
    int o = j >> 8, k = j & 255;
    const float* s = Wout + o * 512 + 2 * k;
    woutT[k * 64 + o] = pkf16(s[0], s[1]);
  }
}

// ---------------------------------------------------------------------------
// x_proj: xp[m, n] = sum_i inputs[m, i] * W_in[n, i]   (m = b*T+ts, f16 out)
// WG = 32 rows of M; thread t owns column n = t, W_in row in 64 regs.
// ---------------------------------------------------------------------------
__global__ __launch_bounds__(512) void xproj_k(
    const float* __restrict__ in, const uint32_t* __restrict__ winT,
    f16* __restrict__ xp) {
  __shared__ uint32_t A[32][64];  // A[r][k] = f16x2 pair of input row r
  const int t = threadIdx.x;
  const int m0 = blockIdx.x * 32;
#pragma unroll
  for (int i = 0; i < 4; i++) {
    int id = i * 512 + t;
    int r = id >> 6, k = id & 63;
    const float* s = in + (m0 + r) * I_ + 2 * k;
    A[r][k] = pkf16(s[0], s[1]);
  }
  uint32_t w[64];
#pragma unroll
  for (int k = 0; k < 64; k++) w[k] = winT[k * 512 + t];
  __syncthreads();
  for (int r = 0; r < 32; r++) {
    float a0 = 0.f, a1 = 0.f, a2 = 0.f, a3 = 0.f;
#pragma unroll
    for (int k4 = 0; k4 < 16; k4++) {
      uint4 hq = *((const uint4*)&A[r][k4 * 4]);
      a0 = dot2(w[4 * k4 + 0], hq.x, a0);
      a1 = dot2(w[4 * k4 + 1], hq.y, a1);
      a2 = dot2(w[4 * k4 + 2], hq.z, a2);
      a3 = dot2(w[4 * k4 + 3], hq.w, a3);
    }
    xp[(m0 + r) * H_ + t] = (f16)((a0 + a1) + (a2 + a3));
  }
}

// ---------------------------------------------------------------------------
// Recurrence: one WG per batch row, 512 threads, thread t owns output row t.
// W_rec row t: pairs 0..215 in VGPRs, pairs 216..255 in LDS (transposed,
// conflict-free). h double-buffered in LDS as f16; one barrier per step.
// ---------------------------------------------------------------------------
#define NV 216
#define NL 40
__global__ __launch_bounds__(512, 2) void rnn_k(
    const uint32_t* __restrict__ wrecT, const f16* __restrict__ xp,
    const float* __restrict__ bias, const float* __restrict__ h0,
    f16* __restrict__ hall, float* __restrict__ hfin) {
  extern __shared__ uint32_t lds[];
  uint32_t* hbuf = lds;           // [2][256] f16x2 pairs (2 KB)
  uint32_t* wldsT = lds + 512;    // [NL][512] (80 KB)
  const int b = blockIdx.x, t = threadIdx.x;

  uint32_t w[NV];
#pragma unroll
  for (int k = 0; k < NV; k++) w[k] = wrecT[k * 512 + t];
#pragma unroll
  for (int c = 0; c < NL; c++) wldsT[c * 512 + t] = wrecT[(NV + c) * 512 + t];

  float hv = h0[b * H_ + t];
  const float bia = bias[t];
  ((f16*)hbuf)[t] = (f16)hv;  // initial h into buffer 0

  const f16* xpp = xp + b * (T_ * H_) + t;
  f16* hap = hall + b * H_ + t;
  float xv = (float)xpp[0];
  __syncthreads();

  for (int ts = 0; ts < T_; ++ts) {
    float xn = 0.f;
    if (ts + 1 < T_) xn = (float)xpp[(ts + 1) * H_];  // prefetch next xp
    const uint32_t* hb = hbuf + (ts & 1) * 256;
    float a0 = 0.f, a1 = 0.f, a2 = 0.f, a3 = 0.f;
#pragma unroll
    for (int k4 = 0; k4 < NV / 4; k4++) {
      uint4 hq = *((const uint4*)(hb + 4 * k4));  // uniform -> broadcast
      a0 = dot2(w[4 * k4 + 0], hq.x, a0);
      a1 = dot2(w[4 * k4 + 1], hq.y, a1);
      a2 = dot2(w[4 * k4 + 2], hq.z, a2);
      a3 = dot2(w[4 * k4 + 3], hq.w, a3);
    }
#pragma unroll
    for (int c4 = 0; c4 < NL / 4; c4++) {
      uint4 hq = *((const uint4*)(hb + NV + 4 * c4));
      a0 = dot2(wldsT[(4 * c4 + 0) * 512 + t], hq.x, a0);
      a1 = dot2(wldsT[(4 * c4 + 1) * 512 + t], hq.y, a1);
      a2 = dot2(wldsT[(4 * c4 + 2) * 512 + t], hq.z, a2);
      a3 = dot2(wldsT[(4 * c4 + 3) * 512 + t], hq.w, a3);
    }
    float pre = ((a0 + a1) + (a2 + a3)) + bia + xv;
    hv = (1.0f - ALPHA_) * hv + ALPHA_ * tanhfast(pre);
    f16 hh = (f16)hv;
    ((f16*)hbuf)[(((ts + 1) & 1) << 9) + t] = hh;  // next buffer
    hap[ts * (B_ * H_)] = hh;                      // hall[ts][b][t]
    xv = xn;
    __syncthreads();
  }
  hfin[b * H_ + t] = hv;
}

// ---------------------------------------------------------------------------
// out[b, ts, o] = sum_h hall[ts][b][h] * W_out[o, h] + b_out[o]
// WG = (b, 32 ts rows); 256 thr = 64 o-cols x 4 row-groups of 8.
// ---------------------------------------------------------------------------
__global__ __launch_bounds__(256) void outgemm_k(
    const f16* __restrict__ hall, const uint32_t* __restrict__ woutT,
    const float* __restrict__ bout, float* __restrict__ out) {
  __shared__ uint32_t A[32][256];  // 32 KB: h rows as f16x2 pairs
  const int bid = blockIdx.x;
  const int b = bid >> 4, ts0 = (bid & 15) * 32;
  const int t = threadIdx.x, o = t & 63, g = t >> 6;
  const uint32_t* hp = (const uint32_t*)hall;
#pragma unroll
  for (int i = 0; i < 32; i++) {
    int id = i * 256 + t;
    int r = id >> 8, k = id & 255;
    A[r][k] = hp[(ts0 + r) * (B_ * H_ / 2) + b * (H_ / 2) + k];
  }
  const float bo = bout[o];
  __syncthreads();
  float acc[8];
#pragma unroll
  for (int r = 0; r < 8; r++) acc[r] = 0.f;
  for (int k4 = 0; k4 < 64; k4++) {
    uint32_t w0 = woutT[(4 * k4 + 0) * 64 + o];
    uint32_t w1 = woutT[(4 * k4 + 1) * 64 + o];
    uint32_t w2 = woutT[(4 * k4 + 2) * 64 + o];
    uint32_t w3 = woutT[(4 * k4 + 3) * 64 + o];
#pragma unroll
    for (int r = 0; r < 8; r++) {
      uint4 hq = *((const uint4*)&A[g * 8 + r][k4 * 4]);
      acc[r] = dot2(w0, hq.x, acc[r]);
      acc[r] = dot2(w1, hq.y, acc[r]);
      acc[r] = dot2(w2, hq.z, acc[r]);
      acc[r] = dot2(w3, hq.w, acc[r]);
    }
  }
#pragma unroll
  for (int r = 0; r < 8; r++)
    out[(b * T_ + ts0 + g * 8 + r) * O_ + o] = acc[r] + bo;
}

extern "C" void kernel_launch(void* const* d_in, const int* in_sizes, int n_in,
                              void* d_out, int out_size, void* d_ws,
                              size_t ws_size, hipStream_t stream) {
  const float* inputs = (const float*)d_in[0];  // [B,T,I]
  const float* h0     = (const float*)d_in[1];  // [B,H]
  const float* Win    = (const float*)d_in[2];  // [H,I]
  const float* Wrec   = (const float*)d_in[3];  // [H,H]
  const float* bias   = (const float*)d_in[4];  // [H]
  const float* Wout   = (const float*)d_in[5];  // [O,H]
  const float* bout   = (const float*)d_in[6];  // [O]
  float* out = (float*)d_out;                   // [B,T,O] then [B,H]

  uint8_t* ws = (uint8_t*)d_ws;
  uint32_t* wrecT = (uint32_t*)(ws);                      // 512 KB
  uint32_t* winT  = (uint32_t*)(ws + (512u << 10));       // 128 KB
  uint32_t* woutT = (uint32_t*)(ws + (640u << 10));       //  64 KB
  f16* xp   = (f16*)(ws + (1u << 20));                    //  32 MB [B,T,H]
  f16* hall = (f16*)(ws + (1u << 20) + (32u << 20));      //  32 MB [T,B,H]

  hipLaunchKernelGGL(pack_w, dim3(704), dim3(256), 0, stream, Wrec, Win, Wout,
                     wrecT, winT, woutT);
  hipLaunchKernelGGL(xproj_k, dim3(32768 / 32), dim3(512), 0, stream, inputs,
                     winT, xp);
  const int rnn_lds = (512 + NL * 512) * 4;  // 83968 B
  hipFuncSetAttribute((const void*)rnn_k,
                      hipFuncAttributeMaxDynamicSharedMemorySize, rnn_lds);
  hipLaunchKernelGGL(rnn_k, dim3(B_), dim3(512), rnn_lds, stream, wrecT, xp,
                     bias, h0, hall, out + B_ * T_ * O_);
  hipLaunchKernelGGL(outgemm_k, dim3(B_ * (T_ / 32)), dim3(256), 0, stream,
                     hall, woutT, bout, out);
}

// Round 2
// 838.979 us; speedup vs baseline: 1.9055x; 1.9055x over previous
//
#include <hip/hip_runtime.h>
#include <stdint.h>

#define B_ 64
#define T_ 512
#define I_ 128
#define H_ 512
#define O_ 64
#define ALPHA_ 0.1f

typedef _Float16 f16;
typedef _Float16 f16x2 __attribute__((ext_vector_type(2)));

__device__ __forceinline__ uint32_t pkf16(float a, float b) {
  f16 ha = (f16)a, hb = (f16)b;
  uint16_t ua = __builtin_bit_cast(uint16_t, ha);
  uint16_t ub = __builtin_bit_cast(uint16_t, hb);
  return (uint32_t)ua | ((uint32_t)ub << 16);
}

__device__ __forceinline__ float dot2(uint32_t w, uint32_t h, float acc) {
#if __has_builtin(__builtin_amdgcn_fdot2)
  return __builtin_amdgcn_fdot2(__builtin_bit_cast(f16x2, w),
                                __builtin_bit_cast(f16x2, h), acc, false);
#else
  f16x2 wv = __builtin_bit_cast(f16x2, w), hv = __builtin_bit_cast(f16x2, h);
  return acc + (float)wv[0] * (float)hv[0] + (float)wv[1] * (float)hv[1];
#endif
}

__device__ __forceinline__ float tanhfast(float x) {
  float e = __expf(2.0f * x);   // inf-safe at both ends
#if __has_builtin(__builtin_amdgcn_rcpf)
  return 1.0f - 2.0f * __builtin_amdgcn_rcpf(e + 1.0f);
#else
  return 1.0f - 2.0f / (e + 1.0f);
#endif
}

// ---------------------------------------------------------------------------
// Pack weights into f16x2 pairs, transposed so per-thread loads are coalesced:
//   wrecT[k*512 + t] = (W_rec[t,2k], W_rec[t,2k+1])   k in [0,256)
//   winT [k*512 + n] = (W_in [n,2k], W_in [n,2k+1])   k in [0,64)
//   woutT[k*64  + o] = (W_out[o,2k], W_out[o,2k+1])   k in [0,256)
// ---------------------------------------------------------------------------
__global__ __launch_bounds__(256) void pack_w(
    const float* __restrict__ Wrec, const float* __restrict__ Win,
    const float* __restrict__ Wout, uint32_t* __restrict__ wrecT,
    uint32_t* __restrict__ winT, uint32_t* __restrict__ woutT) {
  int id = blockIdx.x * 256 + threadIdx.x;
  if (id < 512 * 256) {
    int t = id >> 8, k = id & 255;
    const float* s = Wrec + t * 512 + 2 * k;
    wrecT[k * 512 + t] = pkf16(s[0], s[1]);
  } else if (id < 512 * 256 + 512 * 64) {
    int j = id - 512 * 256;
    int n = j >> 6, k = j & 63;
    const float* s = Win + n * 128 + 2 * k;
    winT[k * 512 + n] = pkf16(s[0], s[1]);
  } else {
    int j = id - (512 * 256 + 512 * 64);
    int o = j >> 8, k = j & 255;
    const float* s = Wout + o * 512 + 2 * k;
    woutT[k * 64 + o] = pkf16(s[0], s[1]);
  }
}

// ---------------------------------------------------------------------------
// x_proj: xp[m, n] = sum_i inputs[m, i] * W_in[n, i]   (m = b*T+ts, f16 out)
// ---------------------------------------------------------------------------
__global__ __launch_bounds__(512) void xproj_k(
    const float* __restrict__ in, const uint32_t* __restrict__ winT,
    f16* __restrict__ xp) {
  __shared__ uint32_t A[32][64];
  const int t = threadIdx.x;
  const int m0 = blockIdx.x * 32;
#pragma unroll
  for (int i = 0; i < 4; i++) {
    int id = i * 512 + t;
    int r = id >> 6, k = id & 63;
    const float* s = in + (m0 + r) * I_ + 2 * k;
    A[r][k] = pkf16(s[0], s[1]);
  }
  uint32_t w[64];
#pragma unroll
  for (int k = 0; k < 64; k++) w[k] = winT[k * 512 + t];
  __syncthreads();
  for (int r = 0; r < 32; r++) {
    float a0 = 0.f, a1 = 0.f, a2 = 0.f, a3 = 0.f;
#pragma unroll
    for (int k4 = 0; k4 < 16; k4++) {
      uint4 hq = *((const uint4*)&A[r][k4 * 4]);
      a0 = dot2(w[4 * k4 + 0], hq.x, a0);
      a1 = dot2(w[4 * k4 + 1], hq.y, a1);
      a2 = dot2(w[4 * k4 + 2], hq.z, a2);
      a3 = dot2(w[4 * k4 + 3], hq.w, a3);
    }
    xp[(m0 + r) * H_ + t] = (f16)((a0 + a1) + (a2 + a3));
  }
}

// ---------------------------------------------------------------------------
// Recurrence: one WG per batch row, 512 threads, thread t owns output row t.
// W_rec row t: pairs 0..NV-1 in VGPRs (waves_per_eu(2,2) pins the 256-VGPR
// budget), pairs NV..255 in LDS as [q][t] uint4 quads (one conflict-free
// ds_read_b128 each). h double-buffered in LDS as f16; raw s_barrier +
// lgkmcnt(0)-only drain per step (vmcnt stays in flight: xp prefetch + hall
// store overlap the next step's compute).
// ---------------------------------------------------------------------------
#define NV 192
#define NL 64
__global__ __attribute__((amdgpu_flat_work_group_size(512, 512),
                          amdgpu_waves_per_eu(2, 2)))
void rnn_k(const uint32_t* __restrict__ wrecT, const f16* __restrict__ xp,
           const float* __restrict__ bias, const float* __restrict__ h0,
           f16* __restrict__ hall, float* __restrict__ hfin) {
  extern __shared__ uint32_t lds[];
  uint32_t* hbuf = lds;                // [2][256] f16x2 pairs (2 KB)
  uint4* wldsQ = (uint4*)(lds + 512);  // [NL/4][512] quads (128 KB)
  const int b = blockIdx.x, t = threadIdx.x;

  uint32_t w[NV];
#pragma unroll
  for (int k = 0; k < NV; k++) w[k] = wrecT[k * 512 + t];
#pragma unroll
  for (int q = 0; q < NL / 4; q++) {
    uint4 v;
    v.x = wrecT[(NV + 4 * q + 0) * 512 + t];
    v.y = wrecT[(NV + 4 * q + 1) * 512 + t];
    v.z = wrecT[(NV + 4 * q + 2) * 512 + t];
    v.w = wrecT[(NV + 4 * q + 3) * 512 + t];
    wldsQ[q * 512 + t] = v;
  }

  float hv = h0[b * H_ + t];
  const float bia = bias[t];
  ((f16*)hbuf)[t] = (f16)hv;  // initial h into buffer 0

  const f16* xpp = xp + b * (T_ * H_) + t;
  f16* hap = hall + b * H_ + t;
  float xv = (float)xpp[0];
  __syncthreads();

  for (int ts = 0; ts < T_; ++ts) {
    float xn = 0.f;
    if (ts + 1 < T_) xn = (float)xpp[(ts + 1) * H_];  // prefetch next xp
    const uint32_t* hb = hbuf + (ts & 1) * 256;
    float a0 = 0.f, a1 = 0.f, a2 = 0.f, a3 = 0.f;
#pragma unroll
    for (int k4 = 0; k4 < NV / 4; k4++) {
      uint4 hq = *((const uint4*)(hb + 4 * k4));  // uniform -> broadcast
      a0 = dot2(w[4 * k4 + 0], hq.x, a0);
      a1 = dot2(w[4 * k4 + 1], hq.y, a1);
      a2 = dot2(w[4 * k4 + 2], hq.z, a2);
      a3 = dot2(w[4 * k4 + 3], hq.w, a3);
    }
#pragma unroll
    for (int q = 0; q < NL / 4; q++) {
      uint4 wq = wldsQ[q * 512 + t];                   // one ds_read_b128
      uint4 hq = *((const uint4*)(hb + NV + 4 * q));   // broadcast
      a0 = dot2(wq.x, hq.x, a0);
      a1 = dot2(wq.y, hq.y, a1);
      a2 = dot2(wq.z, hq.z, a2);
      a3 = dot2(wq.w, hq.w, a3);
    }
    float pre = ((a0 + a1) + (a2 + a3)) + bia + xv;
    hv = (1.0f - ALPHA_) * hv + ALPHA_ * tanhfast(pre);
    f16 hh = (f16)hv;
    ((f16*)hbuf)[(((ts + 1) & 1) << 9) + t] = hh;  // next buffer
    hap[ts * (B_ * H_)] = hh;                      // hall[ts][b][t]
    xv = xn;
    // Drain LDS only (reads retired + my h write visible), NOT vmcnt:
    // xp prefetch + hall store stay in flight across the barrier.
    asm volatile("s_waitcnt lgkmcnt(0)" ::: "memory");
    __builtin_amdgcn_s_barrier();
    asm volatile("" ::: "memory");  // no hoisting of next-iter ds_reads
  }
  hfin[b * H_ + t] = hv;
}

// ---------------------------------------------------------------------------
// out[b, ts, o] = sum_h hall[ts][b][h] * W_out[o, h] + b_out[o]
// ---------------------------------------------------------------------------
__global__ __launch_bounds__(256) void outgemm_k(
    const f16* __restrict__ hall, const uint32_t* __restrict__ woutT,
    const float* __restrict__ bout, float* __restrict__ out) {
  __shared__ uint32_t A[32][256];
  const int bid = blockIdx.x;
  const int b = bid >> 4, ts0 = (bid & 15) * 32;
  const int t = threadIdx.x, o = t & 63, g = t >> 6;
  const uint32_t* hp = (const uint32_t*)hall;
#pragma unroll
  for (int i = 0; i < 32; i++) {
    int id = i * 256 + t;
    int r = id >> 8, k = id & 255;
    A[r][k] = hp[(ts0 + r) * (B_ * H_ / 2) + b * (H_ / 2) + k];
  }
  const float bo = bout[o];
  __syncthreads();
  float acc[8];
#pragma unroll
  for (int r = 0; r < 8; r++) acc[r] = 0.f;
  for (int k4 = 0; k4 < 64; k4++) {
    uint32_t w0 = woutT[(4 * k4 + 0) * 64 + o];
    uint32_t w1 = woutT[(4 * k4 + 1) * 64 + o];
    uint32_t w2 = woutT[(4 * k4 + 2) * 64 + o];
    uint32_t w3 = woutT[(4 * k4 + 3) * 64 + o];
#pragma unroll
    for (int r = 0; r < 8; r++) {
      uint4 hq = *((const uint4*)&A[g * 8 + r][k4 * 4]);
      acc[r] = dot2(w0, hq.x, acc[r]);
      acc[r] = dot2(w1, hq.y, acc[r]);
      acc[r] = dot2(w2, hq.z, acc[r]);
      acc[r] = dot2(w3, hq.w, acc[r]);
    }
  }
#pragma unroll
  for (int r = 0; r < 8; r++)
    out[(b * T_ + ts0 + g * 8 + r) * O_ + o] = acc[r] + bo;
}

extern "C" void kernel_launch(void* const* d_in, const int* in_sizes, int n_in,
                              void* d_out, int out_size, void* d_ws,
                              size_t ws_size, hipStream_t stream) {
  const float* inputs = (const float*)d_in[0];  // [B,T,I]
  const float* h0     = (const float*)d_in[1];  // [B,H]
  const float* Win    = (const float*)d_in[2];  // [H,I]
  const float* Wrec   = (const float*)d_in[3];  // [H,H]
  const float* bias   = (const float*)d_in[4];  // [H]
  const float* Wout   = (const float*)d_in[5];  // [O,H]
  const float* bout   = (const float*)d_in[6];  // [O]
  float* out = (float*)d_out;                   // [B,T,O] then [B,H]

  uint8_t* ws = (uint8_t*)d_ws;
  uint32_t* wrecT = (uint32_t*)(ws);                      // 512 KB
  uint32_t* winT  = (uint32_t*)(ws + (512u << 10));       // 128 KB
  uint32_t* woutT = (uint32_t*)(ws + (640u << 10));       //  64 KB
  f16* xp   = (f16*)(ws + (1u << 20));                    //  32 MB [B,T,H]
  f16* hall = (f16*)(ws + (1u << 20) + (32u << 20));      //  32 MB [T,B,H]

  hipLaunchKernelGGL(pack_w, dim3(704), dim3(256), 0, stream, Wrec, Win, Wout,
                     wrecT, winT, woutT);
  hipLaunchKernelGGL(xproj_k, dim3(32768 / 32), dim3(512), 0, stream, inputs,
                     winT, xp);
  const int rnn_lds = (512 + (NL / 4) * 512 * 4) * 4;  // 133120 B
  hipFuncSetAttribute((const void*)rnn_k,
                      hipFuncAttributeMaxDynamicSharedMemorySize, rnn_lds);
  hipLaunchKernelGGL(rnn_k, dim3(B_), dim3(512), rnn_lds, stream, wrecT, xp,
                     bias, h0, hall, out + B_ * T_ * O_);
  hipLaunchKernelGGL(outgemm_k, dim3(B_ * (T_ / 32)), dim3(256), 0, stream,
                     hall, woutT, bout, out);
}